// Round 10
// baseline (442.660 us; speedup 1.0000x reference)
//
#include <hip/hip_runtime.h>
#include <hip/hip_bf16.h>

using s16x8 = __attribute__((ext_vector_type(8))) short;   // MFMA bf16 A/B fragment
using f32x4 = __attribute__((ext_vector_type(4))) float;   // MFMA C/D fragment
using u32x2 = __attribute__((ext_vector_type(2))) unsigned;

__device__ __forceinline__ ushort f2bf(float f) {
  union { float f; unsigned u; } v; v.f = f;
  unsigned r = v.u + 0x7fffu + ((v.u >> 16) & 1u);   // RNE
  return (ushort)(r >> 16);
}
__device__ __forceinline__ float bf2f(ushort u) {
  return __uint_as_float(((unsigned)u) << 16);
}
__device__ __forceinline__ void gload16(const void* g, void* l) {
  __builtin_amdgcn_global_load_lds(
      (const __attribute__((address_space(1))) void*)g,
      (__attribute__((address_space(3))) void*)l, 16, 0, 0);
}

// ---------------------------------------------------------------------------
// Universal bf16 GEMM (inner loop frozen since r3).
// ---------------------------------------------------------------------------
template<int AF, int BF, bool BIAS, bool RELU, int OUT, bool TRC>
__global__ __launch_bounds__(256, 3)
void gemm(void* __restrict__ Cv, const ushort* __restrict__ A,
          const ushort* __restrict__ B, const float* __restrict__ bias,
          int K, int lda, int ldb, int ldc, long sA, long sB, long sC)
{
  __shared__ ushort As[2][5120];
  __shared__ ushort Bs[2][5120];
  const int tid  = threadIdx.x;
  const int lane = tid & 63, wid = tid >> 6;
  const int gx = gridDim.x, gy = gridDim.y;
  const int lin = blockIdx.y * gx + blockIdx.x;
  int mb, nb;
  if ((gx & 7) == 0) {             // n-major XCD chunking
    const int xcd = lin & 7, idx = lin >> 3, gxp = gx >> 3;
    nb = xcd * gxp + idx / gy;
    mb = idx % gy;
  } else {
    const int nwg = gx * gy;
    const int swz = ((nwg & 7) == 0) ? ((lin & 7) * (nwg >> 3) + (lin >> 3)) : lin;
    mb = swz / gx; nb = swz % gx;
  }
  const int m0 = mb * 128, n0 = nb * 128;
  A += (long)blockIdx.z * sA;
  B += (long)blockIdx.z * sB;

  const int wm = (wid >> 1) * 64, wn = (wid & 1) * 64;
  const int fr = lane & 15, kg = lane >> 4;

  f32x4 acc[4][4];
#pragma unroll
  for (int i = 0; i < 4; ++i)
#pragma unroll
    for (int j = 0; j < 4; ++j)
#pragma unroll
      for (int r = 0; r < 4; ++r) acc[i][j][r] = 0.f;

  auto stageT = [&](const ushort* __restrict__ G, int ld, int c0,
                    ushort* lds, int k0) {
#pragma unroll
    for (int c = 0; c < 2; ++c) {
      const int nb2 = wid * 2 + c;
      const ushort* gp = G + (long)(k0 + (lane >> 1)) * ld + c0 + nb2 * 16 + (lane & 1) * 8;
      gload16(gp, lds + nb2 * 512);
    }
  };
  auto loadN = [&](const ushort* __restrict__ G, int ld, int r0, int k0,
                   uint4& x, uint4& y) {
    const ushort* gp = G + (long)(r0 + (tid >> 1)) * ld + k0 + (tid & 1) * 8;
    x = *(const uint4*)gp;
    y = *(const uint4*)(gp + 16);
  };
  auto writeN = [&](ushort* lds, uint4 x, uint4 y) {
    ushort* p = lds + (tid >> 1) * 40 + (tid & 1) * 8;
    *(uint4*)p = x;
    *(uint4*)(p + 16) = y;
  };
  auto fragN = [&](const ushort* lds, int row) {
    union { s16x8 f; u32x2 h[2]; } u;
    const ushort* p = lds + row * 40 + kg * 4;
    u.h[0] = *(const u32x2*)p;
    u.h[1] = *(const u32x2*)(p + 16);
    return u.f;
  };
  auto fragT = [&](const ushort* lds, int rb) {
    union { s16x8 f; u32x2 h[2]; } u;
    unsigned base = (unsigned)(unsigned long long)(lds + rb * 512) + lane * 8;
    asm volatile("ds_read_b64_tr_b16 %0, %1" : "=v"(u.h[0]) : "v"(base));
    asm volatile("ds_read_b64_tr_b16 %0, %1 offset:512" : "=v"(u.h[1]) : "v"(base));
    return u.f;
  };

  const int NT = K >> 5;
  uint4 ax, ay, bx, by;

  if constexpr (AF == 0) { loadN(A, lda, m0, 0, ax, ay); writeN(As[0], ax, ay); }
  else                   { stageT(A, lda, m0, As[0], 0); }
  if constexpr (BF == 0) { loadN(B, ldb, n0, 0, bx, by); writeN(Bs[0], bx, by); }
  else                   { stageT(B, ldb, n0, Bs[0], 0); }
  __syncthreads();

  for (int t = 0; t < NT; ++t) {
    const int cur = t & 1, nxt = cur ^ 1;
    const bool pre = (t + 1) < NT;
    if (pre) {
      if constexpr (AF == 0) loadN(A, lda, m0, (t + 1) << 5, ax, ay);
      else                   stageT(A, lda, m0, As[nxt], (t + 1) << 5);
      if constexpr (BF == 0) loadN(B, ldb, n0, (t + 1) << 5, bx, by);
      else                   stageT(B, ldb, n0, Bs[nxt], (t + 1) << 5);
    }
    s16x8 af[4], bv[4];
#pragma unroll
    for (int m = 0; m < 4; ++m) {
      if constexpr (AF == 0) af[m] = fragN(As[cur], wm + m * 16 + fr);
      else                   af[m] = fragT(As[cur], (wm >> 4) + m);
    }
#pragma unroll
    for (int n = 0; n < 4; ++n) {
      if constexpr (BF == 0) bv[n] = fragN(Bs[cur], wn + n * 16 + fr);
      else                   bv[n] = fragT(Bs[cur], (wn >> 4) + n);
    }
    if constexpr (AF == 1 || BF == 1) {
      asm volatile("s_waitcnt lgkmcnt(0)");
      __builtin_amdgcn_sched_barrier(0);        // rule #18
    }
    __builtin_amdgcn_s_setprio(1);
#pragma unroll
    for (int m = 0; m < 4; ++m)
#pragma unroll
      for (int n = 0; n < 4; ++n)
        acc[m][n] = __builtin_amdgcn_mfma_f32_16x16x32_bf16(af[m], bv[n], acc[m][n], 0, 0, 0);
    __builtin_amdgcn_s_setprio(0);
    if (pre) {
      if constexpr (AF == 0) writeN(As[nxt], ax, ay);
      if constexpr (BF == 0) writeN(Bs[nxt], bx, by);
    }
    __syncthreads();
  }

  // epilogue. C/D layout (m89/m91): col = lane&15, row = (lane>>4)*4 + reg
#pragma unroll
  for (int m = 0; m < 4; ++m) {
    const int rowb = m0 + wm + m * 16 + kg * 4;
#pragma unroll
    for (int n = 0; n < 4; ++n) {
      const int col = n0 + wn + n * 16 + fr;
      f32x4 v = acc[m][n];
      if constexpr (BIAS) {
#pragma unroll
        for (int r = 0; r < 4; ++r) v[r] += bias[rowb + r];
      }
      if constexpr (RELU) {
#pragma unroll
        for (int r = 0; r < 4; ++r) v[r] = fmaxf(v[r], 0.f);
      }
      if constexpr (TRC) {
        if constexpr (OUT == 0) {
          float* C = (float*)Cv + (long)blockIdx.z * sC;
          float4 s; s.x = v[0]; s.y = v[1]; s.z = v[2]; s.w = v[3];
          *(float4*)(C + (long)col * ldc + rowb) = s;
        } else {
          ushort* C = (ushort*)Cv + (long)blockIdx.z * sC;
          ushort4 s; s.x = f2bf(v[0]); s.y = f2bf(v[1]); s.z = f2bf(v[2]); s.w = f2bf(v[3]);
          *(ushort4*)(C + (long)col * ldc + rowb) = s;
        }
      } else if constexpr (OUT == 0) {
        float* C = (float*)Cv + (long)blockIdx.z * sC;
#pragma unroll
        for (int r = 0; r < 4; ++r) C[(long)(rowb + r) * ldc + col] = v[r];
      } else {
        ushort* C = (ushort*)Cv + (long)blockIdx.z * sC;
#pragma unroll
        for (int r = 0; r < 4; ++r) C[(long)(rowb + r) * ldc + col] = f2bf(v[r]);
      }
    }
  }
}

// ---------------------------------------------------------------------------
// Fused row attention: per (head, 64-row i-tile): S = Q^T K (MFMA), softmax_j,
// out = V P^T (MFMA). Grid 256 = 1 block/CU, 4 waves, 120 KB LDS.
// Layouts: per-head Q/K/V are contiguous [512 cs][256] row-major (stride 256).
// Phase1 uses proven stageT/fragT (both operands same permuted k-map);
// phase3 uses proven loadN/writeN/fragN (stride 40) for V and the same k-map
// read of P from LDS (stride 260).
// ---------------------------------------------------------------------------
__global__ __launch_bounds__(256)
void rowattn_kernel(const ushort* __restrict__ qkv, ushort* __restrict__ out) {
  __shared__ __align__(16) char smem[122880];
  ushort* stg = (ushort*)(smem + 81920);     // phase1 staging dbuf [2][20*512]
  float*  S   = (float*)smem;                // [64][260] fp32 scores
  ushort* P   = (ushort*)(smem + 81920);     // [64][260] bf16 probs (reuses stg)
  ushort* Vs  = (ushort*)smem;               // [2][512*40] V tiles (reuses S)

  const int tid = threadIdx.x, lane = tid & 63, wid = tid >> 6;
  const int fr = lane & 15, kg = lane >> 4;
  const int lin = blockIdx.x;
  const int swz = (lin & 7) * 32 + (lin >> 3);   // XCD x owns heads [8x, 8x+8)
  const int h = swz >> 2, i0 = (swz & 3) * 64;
  const ushort* Qh = qkv + (long)h * 131072;
  const ushort* Kh = qkv + (long)512 * 16384 + (long)h * 131072;
  const ushort* Vh = qkv + (long)1024 * 16384 + (long)h * 131072;

  auto stage1 = [&](ushort* buf, int k0) {
    // 20 chunks of [32 cs][16 cols]: 0..3 = Q cols i0+16c, 4..19 = K cols 16c
    for (int ch = wid; ch < 20; ch += 4) {
      const ushort* G = (ch < 4) ? (Qh + i0 + ch * 16) : (Kh + (ch - 4) * 16);
      gload16(G + (long)(k0 + (lane >> 1)) * 256 + (lane & 1) * 8, buf + ch * 512);
    }
  };
  auto fragT = [&](const ushort* lds, int rb) {
    union { s16x8 f; u32x2 h2[2]; } u;
    unsigned base = (unsigned)(unsigned long long)(lds + rb * 512) + lane * 8;
    asm volatile("ds_read_b64_tr_b16 %0, %1" : "=v"(u.h2[0]) : "v"(base));
    asm volatile("ds_read_b64_tr_b16 %0, %1 offset:512" : "=v"(u.h2[1]) : "v"(base));
    return u.f;
  };

  // ---- phase 1: S[i][j] = sum_cs Q[cs][i] K[cs][j]; wave owns j-slice 64w ----
  {
    f32x4 acc[4][4];
#pragma unroll
    for (int m = 0; m < 4; ++m)
#pragma unroll
      for (int n = 0; n < 4; ++n)
#pragma unroll
        for (int r = 0; r < 4; ++r) acc[m][n][r] = 0.f;

    stage1(stg, 0);
    __syncthreads();
    for (int t = 0; t < 16; ++t) {
      ushort* cur = stg + (t & 1) * 10240;
      ushort* nxt = stg + ((t & 1) ^ 1) * 10240;
      if (t + 1 < 16) stage1(nxt, (t + 1) * 32);
      s16x8 qf[4], kf[4];
#pragma unroll
      for (int m = 0; m < 4; ++m) qf[m] = fragT(cur, m);
#pragma unroll
      for (int n = 0; n < 4; ++n) kf[n] = fragT(cur, 4 + wid * 4 + n);
      asm volatile("s_waitcnt lgkmcnt(0)");
      __builtin_amdgcn_sched_barrier(0);        // rule #18
      __builtin_amdgcn_s_setprio(1);
#pragma unroll
      for (int m = 0; m < 4; ++m)
#pragma unroll
        for (int n = 0; n < 4; ++n)
          acc[m][n] = __builtin_amdgcn_mfma_f32_16x16x32_bf16(qf[m], kf[n], acc[m][n], 0, 0, 0);
      __builtin_amdgcn_s_setprio(0);
      __syncthreads();
    }
    // write S: i_local = m*16+kg*4+r, j = wid*64 + n*16 + fr
#pragma unroll
    for (int m = 0; m < 4; ++m)
#pragma unroll
      for (int n = 0; n < 4; ++n)
#pragma unroll
        for (int r = 0; r < 4; ++r)
          S[(m * 16 + kg * 4 + r) * 260 + wid * 64 + n * 16 + fr] = acc[m][n][r];
  }
  __syncthreads();

  // ---- softmax over j (full 256) per row; 4 lanes per row, shfl_xor reduce ----
  {
    const int row = wid * 16 + (lane >> 2), p = lane & 3;
    float* Sr = S + row * 260 + p * 64;
    float mx = -3.4e38f;
#pragma unroll
    for (int t = 0; t < 16; ++t) {
      float4 v = ((const float4*)Sr)[t];
      mx = fmaxf(mx, fmaxf(fmaxf(v.x, v.y), fmaxf(v.z, v.w)));
    }
    mx = fmaxf(mx, __shfl_xor(mx, 1));
    mx = fmaxf(mx, __shfl_xor(mx, 2));
    float e[64];
    float sum = 0.f;
#pragma unroll
    for (int t = 0; t < 16; ++t) {
      float4 v = ((const float4*)Sr)[t];
      e[4*t+0] = __expf(v.x - mx); e[4*t+1] = __expf(v.y - mx);
      e[4*t+2] = __expf(v.z - mx); e[4*t+3] = __expf(v.w - mx);
      sum += e[4*t+0] + e[4*t+1] + e[4*t+2] + e[4*t+3];
    }
    sum += __shfl_xor(sum, 1);
    sum += __shfl_xor(sum, 2);
    const float rs = 1.f / sum;
    ushort* Pr = P + row * 260 + p * 64;
#pragma unroll
    for (int t = 0; t < 16; ++t) {
      ushort4 o;
      o.x = f2bf(e[4*t+0] * rs); o.y = f2bf(e[4*t+1] * rs);
      o.z = f2bf(e[4*t+2] * rs); o.w = f2bf(e[4*t+3] * rs);
      ((ushort4*)Pr)[t] = o;
    }
  }
  __syncthreads();   // S fully consumed; region A becomes Vs

  // ---- phase 3: out[cs][i] = sum_j V[cs][j] P[i][j]; wave owns cs-slice 128w ----
  {
    f32x4 a2[8][4];
#pragma unroll
    for (int m = 0; m < 8; ++m)
#pragma unroll
      for (int n = 0; n < 4; ++n)
#pragma unroll
        for (int r = 0; r < 4; ++r) a2[m][n][r] = 0.f;

    uint4 vx[4], vy[4];
    auto vload = [&](int k0) {
#pragma unroll
      for (int rp = 0; rp < 4; ++rp) {
        const ushort* gp = Vh + (long)(rp * 128 + (tid >> 1)) * 256 + k0 + (tid & 1) * 8;
        vx[rp] = *(const uint4*)gp;
        vy[rp] = *(const uint4*)(gp + 16);
      }
    };
    auto vwrite = [&](ushort* buf) {
#pragma unroll
      for (int rp = 0; rp < 4; ++rp) {
        ushort* p = buf + (rp * 128 + (tid >> 1)) * 40 + (tid & 1) * 8;
        *(uint4*)p = vx[rp];
        *(uint4*)(p + 16) = vy[rp];
      }
    };
    vload(0); vwrite(Vs);
    __syncthreads();
    for (int t = 0; t < 8; ++t) {
      ushort* cur = Vs + (t & 1) * 20480;
      ushort* nxt = Vs + ((t & 1) ^ 1) * 20480;
      const bool pre = (t + 1) < 8;
      if (pre) vload((t + 1) * 32);
      s16x8 vf[8], pf[4];
#pragma unroll
      for (int m = 0; m < 8; ++m) {
        union { s16x8 f; u32x2 h2[2]; } u;
        const ushort* p = cur + (wid * 128 + m * 16 + fr) * 40 + kg * 4;
        u.h2[0] = *(const u32x2*)p;
        u.h2[1] = *(const u32x2*)(p + 16);
        vf[m] = u.f;
      }
#pragma unroll
      for (int n = 0; n < 4; ++n) {
        union { s16x8 f; u32x2 h2[2]; } u;
        const ushort* p = P + (n * 16 + fr) * 260 + t * 32 + kg * 4;
        u.h2[0] = *(const u32x2*)p;
        u.h2[1] = *(const u32x2*)(p + 16);
        pf[n] = u.f;
      }
      __builtin_amdgcn_s_setprio(1);
#pragma unroll
      for (int m = 0; m < 8; ++m)
#pragma unroll
        for (int n = 0; n < 4; ++n)
          a2[m][n] = __builtin_amdgcn_mfma_f32_16x16x32_bf16(vf[m], pf[n], a2[m][n], 0, 0, 0);
      __builtin_amdgcn_s_setprio(0);
      if (pre) vwrite(nxt);
      __syncthreads();
    }
    ushort* Oh = out + (long)h * 131072;
#pragma unroll
    for (int m = 0; m < 8; ++m) {
      const int cs = wid * 128 + m * 16 + kg * 4;
#pragma unroll
      for (int n = 0; n < 4; ++n) {
        const int i = i0 + n * 16 + fr;
#pragma unroll
        for (int r = 0; r < 4; ++r)
          Oh[(long)(cs + r) * 256 + i] = f2bf(a2[m][n][r]);
      }
    }
  }
}

// fp32 -> bf16 bulk convert
__global__ __launch_bounds__(256)
void cvt_kernel(const float4* __restrict__ in, ushort4* __restrict__ out, int n4) {
  int i = blockIdx.x * 256 + threadIdx.x;
  if (i < n4) {
    float4 f = in[i];
    ushort4 u; u.x = f2bf(f.x); u.y = f2bf(f.y); u.z = f2bf(f.z); u.w = f2bf(f.w);
    out[i] = u;
  }
}

// Column attention, XCD-swizzled. bf16 in/out.
__global__ __launch_bounds__(256)
void colattn_kernel(const ushort* __restrict__ qkv, ushort* __restrict__ out) {
  __shared__ float q[4][8][64], kk[4][8][64], vv[4][8][64];
  const int lin = blockIdx.x;
  const int swz = (lin & 7) * 512 + (lin >> 3);   // bijective, 4096 % 8 == 0
  const int h = swz >> 6;
  const int l0 = (swz & 63) * 4;
  const int tid = threadIdx.x;
  for (int i = tid; i < 1536; i += 256) {
    int m = i >> 9;              // 0:q 1:k 2:v
    int e = i & 511;             // c*64+s
    int c = e >> 6, s = e & 63;
    ushort4 u = *(const ushort4*)(qkv + (long)(m * 512 + h * 8 + c) * 16384 + s * 256 + l0);
    float* dst = (m == 0) ? &q[0][0][0] : (m == 1) ? &kk[0][0][0] : &vv[0][0][0];
    dst[e] = bf2f(u.x); dst[512 + e] = bf2f(u.y);
    dst[1024 + e] = bf2f(u.z); dst[1536 + e] = bf2f(u.w);
  }
  __syncthreads();
  const int li = tid >> 6, lane = tid & 63;
  float qi[8];
#pragma unroll
  for (int c = 0; c < 8; ++c) qi[c] = q[li][c][lane];
  float sc[64];
#pragma unroll
  for (int j4 = 0; j4 < 16; ++j4) {
    float ax = 0.f, ay = 0.f, az = 0.f, aw = 0.f;
#pragma unroll
    for (int c = 0; c < 8; ++c) {
      float4 k4 = *(const float4*)&kk[li][c][j4 * 4];
      ax = fmaf(qi[c], k4.x, ax); ay = fmaf(qi[c], k4.y, ay);
      az = fmaf(qi[c], k4.z, az); aw = fmaf(qi[c], k4.w, aw);
    }
    sc[j4 * 4 + 0] = ax; sc[j4 * 4 + 1] = ay;
    sc[j4 * 4 + 2] = az; sc[j4 * 4 + 3] = aw;
  }
  float mx = sc[0];
#pragma unroll
  for (int j = 1; j < 64; ++j) mx = fmaxf(mx, sc[j]);
  float sum = 0.f;
#pragma unroll
  for (int j = 0; j < 64; ++j) { sc[j] = __expf(sc[j] - mx); sum += sc[j]; }
  const float rs = 1.f / sum;
  float o[8];
#pragma unroll
  for (int c = 0; c < 8; ++c) o[c] = 0.f;
#pragma unroll
  for (int j4 = 0; j4 < 16; ++j4) {
    const float px = sc[j4 * 4 + 0], py = sc[j4 * 4 + 1];
    const float pz = sc[j4 * 4 + 2], pw = sc[j4 * 4 + 3];
#pragma unroll
    for (int c = 0; c < 8; ++c) {
      float4 v4 = *(const float4*)&vv[li][c][j4 * 4];
      o[c] = fmaf(px, v4.x, fmaf(py, v4.y, fmaf(pz, v4.z, fmaf(pw, v4.w, o[c]))));
    }
  }
#pragma unroll
  for (int c = 0; c < 8; ++c) q[li][c][lane] = o[c] * rs;
  __syncthreads();
  for (int i = tid; i < 512; i += 256) {
    int c = i >> 6, s = i & 63;
    ushort4 u;
    u.x = f2bf(q[0][c][s]); u.y = f2bf(q[1][c][s]);
    u.z = f2bf(q[2][c][s]); u.w = f2bf(q[3][c][s]);
    *(ushort4*)(out + (long)(h * 8 + c) * 16384 + s * 256 + l0) = u;
  }
}

// Channel LN, bf16 in (fp32 math). OM: 0 = bf16 out, 1 = fp32 out.
template<bool RES, int OM>
__global__ __launch_bounds__(1024)
void ln_kernel(void* __restrict__ outv, const ushort* __restrict__ a,
               const ushort* __restrict__ b, const float* __restrict__ w,
               const float* __restrict__ bias) {
  __shared__ float red[2][16][64];
  const int lane = threadIdx.x & 63, seg = threadIdx.x >> 6;
  const long n = (long)blockIdx.x * 64 + lane;
  const int d0 = seg * 32;
  float v[32];
  float s1 = 0.f, s2 = 0.f;
#pragma unroll
  for (int i = 0; i < 32; ++i) {
    float t = bf2f(a[(long)(d0 + i) * 16384 + n]);
    if constexpr (RES) t += bf2f(b[(long)(d0 + i) * 16384 + n]);
    v[i] = t; s1 += t; s2 += t * t;
  }
  red[0][seg][lane] = s1; red[1][seg][lane] = s2;
  __syncthreads();
  s1 = 0.f; s2 = 0.f;
#pragma unroll
  for (int s = 0; s < 16; ++s) { s1 += red[0][s][lane]; s2 += red[1][s][lane]; }
  const float mean = s1 * (1.f / 512.f);
  const float var = s2 * (1.f / 512.f) - mean * mean;
  const float rstd = rsqrtf(var + 1e-5f);
#pragma unroll
  for (int i = 0; i < 32; ++i) {
    float o = (v[i] - mean) * rstd * w[d0 + i] + bias[d0 + i];
    if constexpr (OM == 0) ((ushort*)outv)[(long)(d0 + i) * 16384 + n] = f2bf(o);
    else                   ((float*)outv)[(long)(d0 + i) * 16384 + n] = o;
  }
}

// Fused LN8+LN9: out = LN( LN(a+b)*w1+b1 )*w2+b2, bf16 in/out.
__global__ __launch_bounds__(1024)
void ln_fuse_kernel(ushort* __restrict__ out, const ushort* __restrict__ a,
                    const ushort* __restrict__ b,
                    const float* __restrict__ w1, const float* __restrict__ b1,
                    const float* __restrict__ w2, const float* __restrict__ b2) {
  __shared__ float red[2][16][64];
  const int lane = threadIdx.x & 63, seg = threadIdx.x >> 6;
  const long n = (long)blockIdx.x * 64 + lane;
  const int d0 = seg * 32;
  float v[32];
  float s1 = 0.f, s2 = 0.f;
#pragma unroll
  for (int i = 0; i < 32; ++i) {
    float t = bf2f(a[(long)(d0 + i) * 16384 + n]) + bf2f(b[(long)(d0 + i) * 16384 + n]);
    v[i] = t; s1 += t; s2 += t * t;
  }
  red[0][seg][lane] = s1; red[1][seg][lane] = s2;
  __syncthreads();
  s1 = 0.f; s2 = 0.f;
#pragma unroll
  for (int s = 0; s < 16; ++s) { s1 += red[0][s][lane]; s2 += red[1][s][lane]; }
  float mean = s1 * (1.f / 512.f);
  float var = s2 * (1.f / 512.f) - mean * mean;
  float rstd = rsqrtf(var + 1e-5f);
  __syncthreads();
  s1 = 0.f; s2 = 0.f;
#pragma unroll
  for (int i = 0; i < 32; ++i) {
    float y = (v[i] - mean) * rstd * w1[d0 + i] + b1[d0 + i];
    v[i] = y; s1 += y; s2 += y * y;
  }
  red[0][seg][lane] = s1; red[1][seg][lane] = s2;
  __syncthreads();
  s1 = 0.f; s2 = 0.f;
#pragma unroll
  for (int s = 0; s < 16; ++s) { s1 += red[0][s][lane]; s2 += red[1][s][lane]; }
  mean = s1 * (1.f / 512.f);
  var = s2 * (1.f / 512.f) - mean * mean;
  rstd = rsqrtf(var + 1e-5f);
#pragma unroll
  for (int i = 0; i < 32; ++i) {
    float o = (v[i] - mean) * rstd * w2[d0 + i] + b2[d0 + i];
    out[(long)(d0 + i) * 16384 + n] = f2bf(o);
  }
}

extern "C" void kernel_launch(void* const* d_in, const int* in_sizes, int n_in,
                              void* d_out, int out_size, void* d_ws, size_t ws_size,
                              hipStream_t stream) {
  const float* x     = (const float*)d_in[0];
  const float* w_row = (const float*)d_in[1];
  const float* b_row = (const float*)d_in[2];
  const float* w_col = (const float*)d_in[3];
  const float* b_col = (const float*)d_in[4];
  const float* w_an1 = (const float*)d_in[5];
  const float* b_an1 = (const float*)d_in[6];
  const float* w_an2 = (const float*)d_in[7];
  const float* b_an2 = (const float*)d_in[8];
  const float* w_ff1 = (const float*)d_in[9];
  const float* b_ff1 = (const float*)d_in[10];
  const float* w_ff2 = (const float*)d_in[11];
  const float* b_ff2 = (const float*)d_in[12];
  const float* w_ln1 = (const float*)d_in[13];
  const float* b_ln1 = (const float*)d_in[14];
  const float* w_ln2 = (const float*)d_in[15];
  const float* b_ln2 = (const float*)d_in[16];
  float* outp = (float*)d_out;

  char* Wb = (char*)d_ws;
  ushort* big    = (ushort*)Wb;                       // [2048][16384] bf16: qkv / ff1
  ushort* colbf  = (ushort*)(Wb + 71303168ull);       // col-attn out bf16
  ushort* xbf    = (ushort*)(Wb + 100663296ull);      // x bf16 (dead after ln5)
  ushort* ff2bf  = (ushort*)(Wb + 100663296ull);      //   reused: ff2 out
  ushort* rowbf  = (ushort*)(Wb + 118489088ull);      // row-attn out bf16
  ushort* out1bf = (ushort*)(Wb + 136314880ull);      // LN5 out bf16
  ushort* hbf    = (ushort*)(Wb + 154140672ull);      // fused-LN out bf16
  ushort* wrowb  = (ushort*)(Wb + 171966464ull);      // weights bf16
  ushort* wcolb = wrowb + 786432;
  ushort* wff1b = wcolb + 786432;
  ushort* wff2b = wff1b + 1048576;

  const dim3 blk(256);

  // 0. bf16 conversions (x + weights)
  cvt_kernel<<<8192, blk, 0, stream>>>((const float4*)x, (ushort4*)xbf, 2097152);
  cvt_kernel<<<768,  blk, 0, stream>>>((const float4*)w_row, (ushort4*)wrowb, 196608);
  cvt_kernel<<<768,  blk, 0, stream>>>((const float4*)w_col, (ushort4*)wcolb, 196608);
  cvt_kernel<<<1024, blk, 0, stream>>>((const float4*)w_ff1, (ushort4*)wff1b, 262144);
  cvt_kernel<<<1024, blk, 0, stream>>>((const float4*)w_ff2, (ushort4*)wff2b, 262144);

  // 1. qkv_row = W_row * x + b_row   [1536][16384] bf16
  gemm<0,1,true,false,1,false><<<dim3(128, 12, 1), blk, 0, stream>>>(
      big, wrowb, xbf, b_row, 512, 512, 16384, 16384, 0, 0, 0);
  // 2-4. fused row attention -> rowbf
  rowattn_kernel<<<256, blk, 0, stream>>>(big, rowbf);
  // 5. out1 = LN(x + row_out) -> out1bf
  ln_kernel<true, 0><<<256, dim3(1024), 0, stream>>>(out1bf, xbf, rowbf, w_an1, b_an1);
  // 6. qkv_col = W_col * out1 + b_col  -> big (bf16)
  gemm<0,1,true,false,1,false><<<dim3(128, 12, 1), blk, 0, stream>>>(
      big, wcolb, out1bf, b_col, 512, 512, 16384, 16384, 0, 0, 0);
  // 7. column attention -> colbf
  colattn_kernel<<<4096, blk, 0, stream>>>(big, colbf);
  // 8+9. h = LN(LN(out1 + col_out)*w_an2+b_an2)*w_ln1+b_ln1 -> hbf
  ln_fuse_kernel<<<256, dim3(1024), 0, stream>>>(hbf, out1bf, colbf,
                                                 w_an2, b_an2, w_ln1, b_ln1);
  // 10. ff1 = relu(W_ff1 * h + b_ff1) -> big [2048][16384] bf16
  gemm<0,1,true,true,1,false><<<dim3(128, 16, 1), blk, 0, stream>>>(
      big, wff1b, hbf, b_ff1, 512, 512, 16384, 16384, 0, 0, 0);
  // 11. ff2 = W_ff2 * ff1 + b_ff2 -> ff2bf
  gemm<0,1,true,false,1,false><<<dim3(128, 4, 1), blk, 0, stream>>>(
      ff2bf, wff2b, big, b_ff2, 2048, 2048, 16384, 16384, 0, 0, 0);
  // 12. out = LN(h + ff2) -> d_out (fp32)
  ln_kernel<true, 1><<<256, dim3(1024), 0, stream>>>(outp, hbf, ff2bf, w_ln2, b_ln2);
}

// Round 11
// 426.725 us; speedup vs baseline: 1.0373x; 1.0373x over previous
//
#include <hip/hip_runtime.h>
#include <hip/hip_bf16.h>

using s16x8 = __attribute__((ext_vector_type(8))) short;   // MFMA bf16 A/B fragment
using f32x4 = __attribute__((ext_vector_type(4))) float;   // MFMA C/D fragment
using u32x2 = __attribute__((ext_vector_type(2))) unsigned;

__device__ __forceinline__ ushort f2bf(float f) {
  union { float f; unsigned u; } v; v.f = f;
  unsigned r = v.u + 0x7fffu + ((v.u >> 16) & 1u);   // RNE
  return (ushort)(r >> 16);
}
__device__ __forceinline__ float bf2f(ushort u) {
  return __uint_as_float(((unsigned)u) << 16);
}
__device__ __forceinline__ void gload16(const void* g, void* l) {
  __builtin_amdgcn_global_load_lds(
      (const __attribute__((address_space(1))) void*)g,
      (__attribute__((address_space(3))) void*)l, 16, 0, 0);
}

// ---------------------------------------------------------------------------
// Universal bf16 GEMM (inner loop frozen since r3).
// ---------------------------------------------------------------------------
template<int AF, int BF, bool BIAS, bool RELU, int OUT, bool TRC>
__global__ __launch_bounds__(256, 3)
void gemm(void* __restrict__ Cv, const ushort* __restrict__ A,
          const ushort* __restrict__ B, const float* __restrict__ bias,
          int K, int lda, int ldb, int ldc, long sA, long sB, long sC)
{
  __shared__ ushort As[2][5120];
  __shared__ ushort Bs[2][5120];
  const int tid  = threadIdx.x;
  const int lane = tid & 63, wid = tid >> 6;
  const int gx = gridDim.x, gy = gridDim.y;
  const int lin = blockIdx.y * gx + blockIdx.x;
  int mb, nb;
  if ((gx & 7) == 0) {             // n-major XCD chunking
    const int xcd = lin & 7, idx = lin >> 3, gxp = gx >> 3;
    nb = xcd * gxp + idx / gy;
    mb = idx % gy;
  } else {
    const int nwg = gx * gy;
    const int swz = ((nwg & 7) == 0) ? ((lin & 7) * (nwg >> 3) + (lin >> 3)) : lin;
    mb = swz / gx; nb = swz % gx;
  }
  const int m0 = mb * 128, n0 = nb * 128;
  A += (long)blockIdx.z * sA;
  B += (long)blockIdx.z * sB;

  const int wm = (wid >> 1) * 64, wn = (wid & 1) * 64;
  const int fr = lane & 15, kg = lane >> 4;

  f32x4 acc[4][4];
#pragma unroll
  for (int i = 0; i < 4; ++i)
#pragma unroll
    for (int j = 0; j < 4; ++j)
#pragma unroll
      for (int r = 0; r < 4; ++r) acc[i][j][r] = 0.f;

  auto stageT = [&](const ushort* __restrict__ G, int ld, int c0,
                    ushort* lds, int k0) {
#pragma unroll
    for (int c = 0; c < 2; ++c) {
      const int nb2 = wid * 2 + c;
      const ushort* gp = G + (long)(k0 + (lane >> 1)) * ld + c0 + nb2 * 16 + (lane & 1) * 8;
      gload16(gp, lds + nb2 * 512);
    }
  };
  auto loadN = [&](const ushort* __restrict__ G, int ld, int r0, int k0,
                   uint4& x, uint4& y) {
    const ushort* gp = G + (long)(r0 + (tid >> 1)) * ld + k0 + (tid & 1) * 8;
    x = *(const uint4*)gp;
    y = *(const uint4*)(gp + 16);
  };
  auto writeN = [&](ushort* lds, uint4 x, uint4 y) {
    ushort* p = lds + (tid >> 1) * 40 + (tid & 1) * 8;
    *(uint4*)p = x;
    *(uint4*)(p + 16) = y;
  };
  auto fragN = [&](const ushort* lds, int row) {
    union { s16x8 f; u32x2 h[2]; } u;
    const ushort* p = lds + row * 40 + kg * 4;
    u.h[0] = *(const u32x2*)p;
    u.h[1] = *(const u32x2*)(p + 16);
    return u.f;
  };
  auto fragT = [&](const ushort* lds, int rb) {
    union { s16x8 f; u32x2 h[2]; } u;
    unsigned base = (unsigned)(unsigned long long)(lds + rb * 512) + lane * 8;
    asm volatile("ds_read_b64_tr_b16 %0, %1" : "=v"(u.h[0]) : "v"(base));
    asm volatile("ds_read_b64_tr_b16 %0, %1 offset:512" : "=v"(u.h[1]) : "v"(base));
    return u.f;
  };

  const int NT = K >> 5;
  uint4 ax, ay, bx, by;

  if constexpr (AF == 0) { loadN(A, lda, m0, 0, ax, ay); writeN(As[0], ax, ay); }
  else                   { stageT(A, lda, m0, As[0], 0); }
  if constexpr (BF == 0) { loadN(B, ldb, n0, 0, bx, by); writeN(Bs[0], bx, by); }
  else                   { stageT(B, ldb, n0, Bs[0], 0); }
  __syncthreads();

  for (int t = 0; t < NT; ++t) {
    const int cur = t & 1, nxt = cur ^ 1;
    const bool pre = (t + 1) < NT;
    if (pre) {
      if constexpr (AF == 0) loadN(A, lda, m0, (t + 1) << 5, ax, ay);
      else                   stageT(A, lda, m0, As[nxt], (t + 1) << 5);
      if constexpr (BF == 0) loadN(B, ldb, n0, (t + 1) << 5, bx, by);
      else                   stageT(B, ldb, n0, Bs[nxt], (t + 1) << 5);
    }
    s16x8 af[4], bv[4];
#pragma unroll
    for (int m = 0; m < 4; ++m) {
      if constexpr (AF == 0) af[m] = fragN(As[cur], wm + m * 16 + fr);
      else                   af[m] = fragT(As[cur], (wm >> 4) + m);
    }
#pragma unroll
    for (int n = 0; n < 4; ++n) {
      if constexpr (BF == 0) bv[n] = fragN(Bs[cur], wn + n * 16 + fr);
      else                   bv[n] = fragT(Bs[cur], (wn >> 4) + n);
    }
    if constexpr (AF == 1 || BF == 1) {
      asm volatile("s_waitcnt lgkmcnt(0)");
      __builtin_amdgcn_sched_barrier(0);        // rule #18
    }
    __builtin_amdgcn_s_setprio(1);
#pragma unroll
    for (int m = 0; m < 4; ++m)
#pragma unroll
      for (int n = 0; n < 4; ++n)
        acc[m][n] = __builtin_amdgcn_mfma_f32_16x16x32_bf16(af[m], bv[n], acc[m][n], 0, 0, 0);
    __builtin_amdgcn_s_setprio(0);
    if (pre) {
      if constexpr (AF == 0) writeN(As[nxt], ax, ay);
      if constexpr (BF == 0) writeN(Bs[nxt], bx, by);
    }
    __syncthreads();
  }

  // epilogue. C/D layout (m89/m91): col = lane&15, row = (lane>>4)*4 + reg
#pragma unroll
  for (int m = 0; m < 4; ++m) {
    const int rowb = m0 + wm + m * 16 + kg * 4;
#pragma unroll
    for (int n = 0; n < 4; ++n) {
      const int col = n0 + wn + n * 16 + fr;
      f32x4 v = acc[m][n];
      if constexpr (BIAS) {
#pragma unroll
        for (int r = 0; r < 4; ++r) v[r] += bias[rowb + r];
      }
      if constexpr (RELU) {
#pragma unroll
        for (int r = 0; r < 4; ++r) v[r] = fmaxf(v[r], 0.f);
      }
      if constexpr (TRC) {
        if constexpr (OUT == 0) {
          float* C = (float*)Cv + (long)blockIdx.z * sC;
          float4 s; s.x = v[0]; s.y = v[1]; s.z = v[2]; s.w = v[3];
          *(float4*)(C + (long)col * ldc + rowb) = s;
        } else {
          ushort* C = (ushort*)Cv + (long)blockIdx.z * sC;
          ushort4 s; s.x = f2bf(v[0]); s.y = f2bf(v[1]); s.z = f2bf(v[2]); s.w = f2bf(v[3]);
          *(ushort4*)(C + (long)col * ldc + rowb) = s;
        }
      } else if constexpr (OUT == 0) {
        float* C = (float*)Cv + (long)blockIdx.z * sC;
#pragma unroll
        for (int r = 0; r < 4; ++r) C[(long)(rowb + r) * ldc + col] = v[r];
      } else {
        ushort* C = (ushort*)Cv + (long)blockIdx.z * sC;
#pragma unroll
        for (int r = 0; r < 4; ++r) C[(long)(rowb + r) * ldc + col] = f2bf(v[r]);
      }
    }
  }
}

// fp32 -> bf16 bulk convert (x)
__global__ __launch_bounds__(256)
void cvt_kernel(const float4* __restrict__ in, ushort4* __restrict__ out, int n4) {
  int i = blockIdx.x * 256 + threadIdx.x;
  if (i < n4) {
    float4 f = in[i];
    ushort4 u; u.x = f2bf(f.x); u.y = f2bf(f.y); u.z = f2bf(f.z); u.w = f2bf(f.w);
    out[i] = u;
  }
}

// All 4 weight conversions in one launch (block-range dispatch).
__global__ __launch_bounds__(256)
void cvtw_kernel(const float4* __restrict__ w0, ushort4* __restrict__ o0,
                 const float4* __restrict__ w1, ushort4* __restrict__ o1,
                 const float4* __restrict__ w2, ushort4* __restrict__ o2,
                 const float4* __restrict__ w3, ushort4* __restrict__ o3) {
  const int b = blockIdx.x;
  const float4* in; ushort4* out; int i;
  if (b < 768)       { in = w0; out = o0; i = b * 256 + threadIdx.x; }
  else if (b < 1536) { in = w1; out = o1; i = (b - 768) * 256 + threadIdx.x; }
  else if (b < 2560) { in = w2; out = o2; i = (b - 1536) * 256 + threadIdx.x; }
  else               { in = w3; out = o3; i = (b - 2560) * 256 + threadIdx.x; }
  float4 f = in[i];
  ushort4 u; u.x = f2bf(f.x); u.y = f2bf(f.y); u.z = f2bf(f.z); u.w = f2bf(f.w);
  out[i] = u;
}

// Row softmax over last dim of [16384][256] fp32 scores -> bf16 P
__global__ __launch_bounds__(256)
void softmax_kernel(const float* __restrict__ S, ushort* __restrict__ P) {
  const int row = blockIdx.x * 4 + (threadIdx.x >> 6);
  const int lane = threadIdx.x & 63;
  float4 v = *(const float4*)(S + (long)row * 256 + lane * 4);
  float mx = fmaxf(fmaxf(v.x, v.y), fmaxf(v.z, v.w));
#pragma unroll
  for (int off = 32; off; off >>= 1) mx = fmaxf(mx, __shfl_xor(mx, off));
  v.x = __expf(v.x - mx); v.y = __expf(v.y - mx);
  v.z = __expf(v.z - mx); v.w = __expf(v.w - mx);
  float s = v.x + v.y + v.z + v.w;
#pragma unroll
  for (int off = 32; off; off >>= 1) s += __shfl_xor(s, off);
  const float r = 1.f / s;
  ushort4 o;
  o.x = f2bf(v.x * r); o.y = f2bf(v.y * r); o.z = f2bf(v.z * r); o.w = f2bf(v.w * r);
  *(ushort4*)(P + (long)row * 256 + lane * 4) = o;
}

// Column attention, XCD-swizzled, 2-deep software-pipelined LDS reads
// (double-buffered ka/kb, va/vb register sets hide ~120cy uniform-read latency).
__global__ __launch_bounds__(256)
void colattn_kernel(const ushort* __restrict__ qkv, ushort* __restrict__ out) {
  __shared__ float q[4][8][64], kk[4][8][64], vv[4][8][64];
  const int lin = blockIdx.x;
  const int swz = (lin & 7) * 512 + (lin >> 3);   // bijective, 4096 % 8 == 0
  const int h = swz >> 6;
  const int l0 = (swz & 63) * 4;
  const int tid = threadIdx.x;
  for (int i = tid; i < 1536; i += 256) {
    int m = i >> 9;              // 0:q 1:k 2:v
    int e = i & 511;             // c*64+s
    int c = e >> 6, s = e & 63;
    ushort4 u = *(const ushort4*)(qkv + (long)(m * 512 + h * 8 + c) * 16384 + s * 256 + l0);
    float* dst = (m == 0) ? &q[0][0][0] : (m == 1) ? &kk[0][0][0] : &vv[0][0][0];
    dst[e] = bf2f(u.x); dst[512 + e] = bf2f(u.y);
    dst[1024 + e] = bf2f(u.z); dst[1536 + e] = bf2f(u.w);
  }
  __syncthreads();
  const int li = tid >> 6, lane = tid & 63;   // lane = query index i (s)
  float qi[8];
#pragma unroll
  for (int c = 0; c < 8; ++c) qi[c] = q[li][c][lane];
  float sc[64];
  {
    float4 ka[8], kb[8];
#pragma unroll
    for (int c = 0; c < 8; ++c) ka[c] = *(const float4*)&kk[li][c][0];
#pragma unroll
    for (int j4 = 0; j4 < 16; ++j4) {
      const float4* cur = (j4 & 1) ? kb : ka;   // unrolled: folds to static
      float4* nxt = (j4 & 1) ? ka : kb;
      if (j4 < 15) {
#pragma unroll
        for (int c = 0; c < 8; ++c) nxt[c] = *(const float4*)&kk[li][c][(j4 + 1) * 4];
      }
      float ax = 0.f, ay = 0.f, az = 0.f, aw = 0.f;
#pragma unroll
      for (int c = 0; c < 8; ++c) {
        ax = fmaf(qi[c], cur[c].x, ax); ay = fmaf(qi[c], cur[c].y, ay);
        az = fmaf(qi[c], cur[c].z, az); aw = fmaf(qi[c], cur[c].w, aw);
      }
      sc[j4 * 4 + 0] = ax; sc[j4 * 4 + 1] = ay;
      sc[j4 * 4 + 2] = az; sc[j4 * 4 + 3] = aw;
    }
  }
  float mx = sc[0];
#pragma unroll
  for (int j = 1; j < 64; ++j) mx = fmaxf(mx, sc[j]);
  float sum = 0.f;
#pragma unroll
  for (int j = 0; j < 64; ++j) { sc[j] = __expf(sc[j] - mx); sum += sc[j]; }
  const float rs = 1.f / sum;
  float o[8];
#pragma unroll
  for (int c = 0; c < 8; ++c) o[c] = 0.f;
  {
    float4 va[8], vb[8];
#pragma unroll
    for (int c = 0; c < 8; ++c) va[c] = *(const float4*)&vv[li][c][0];
#pragma unroll
    for (int j4 = 0; j4 < 16; ++j4) {
      const float4* cur = (j4 & 1) ? vb : va;
      float4* nxt = (j4 & 1) ? va : vb;
      if (j4 < 15) {
#pragma unroll
        for (int c = 0; c < 8; ++c) nxt[c] = *(const float4*)&vv[li][c][(j4 + 1) * 4];
      }
      const float px = sc[j4 * 4 + 0], py = sc[j4 * 4 + 1];
      const float pz = sc[j4 * 4 + 2], pw = sc[j4 * 4 + 3];
#pragma unroll
      for (int c = 0; c < 8; ++c) {
        o[c] = fmaf(px, cur[c].x, fmaf(py, cur[c].y,
               fmaf(pz, cur[c].z, fmaf(pw, cur[c].w, o[c]))));
      }
    }
  }
#pragma unroll
  for (int c = 0; c < 8; ++c) q[li][c][lane] = o[c] * rs;
  __syncthreads();
  for (int i = tid; i < 512; i += 256) {
    int c = i >> 6, s = i & 63;
    ushort4 u;
    u.x = f2bf(q[0][c][s]); u.y = f2bf(q[1][c][s]);
    u.z = f2bf(q[2][c][s]); u.w = f2bf(q[3][c][s]);
    *(ushort4*)(out + (long)(h * 8 + c) * 16384 + s * 256 + l0) = u;
  }
}

// Channel LN, bf16 in (fp32 math). OM: 0 = bf16 out, 1 = fp32 out.
template<bool RES, int OM>
__global__ __launch_bounds__(1024)
void ln_kernel(void* __restrict__ outv, const ushort* __restrict__ a,
               const ushort* __restrict__ b, const float* __restrict__ w,
               const float* __restrict__ bias) {
  __shared__ float red[2][16][64];
  const int lane = threadIdx.x & 63, seg = threadIdx.x >> 6;
  const long n = (long)blockIdx.x * 64 + lane;
  const int d0 = seg * 32;
  float v[32];
  float s1 = 0.f, s2 = 0.f;
#pragma unroll
  for (int i = 0; i < 32; ++i) {
    float t = bf2f(a[(long)(d0 + i) * 16384 + n]);
    if constexpr (RES) t += bf2f(b[(long)(d0 + i) * 16384 + n]);
    v[i] = t; s1 += t; s2 += t * t;
  }
  red[0][seg][lane] = s1; red[1][seg][lane] = s2;
  __syncthreads();
  s1 = 0.f; s2 = 0.f;
#pragma unroll
  for (int s = 0; s < 16; ++s) { s1 += red[0][s][lane]; s2 += red[1][s][lane]; }
  const float mean = s1 * (1.f / 512.f);
  const float var = s2 * (1.f / 512.f) - mean * mean;
  const float rstd = rsqrtf(var + 1e-5f);
#pragma unroll
  for (int i = 0; i < 32; ++i) {
    float o = (v[i] - mean) * rstd * w[d0 + i] + bias[d0 + i];
    if constexpr (OM == 0) ((ushort*)outv)[(long)(d0 + i) * 16384 + n] = f2bf(o);
    else                   ((float*)outv)[(long)(d0 + i) * 16384 + n] = o;
  }
}

// Fused LN8+LN9: out = LN( LN(a+b)*w1+b1 )*w2+b2, bf16 in/out.
__global__ __launch_bounds__(1024)
void ln_fuse_kernel(ushort* __restrict__ out, const ushort* __restrict__ a,
                    const ushort* __restrict__ b,
                    const float* __restrict__ w1, const float* __restrict__ b1,
                    const float* __restrict__ w2, const float* __restrict__ b2) {
  __shared__ float red[2][16][64];
  const int lane = threadIdx.x & 63, seg = threadIdx.x >> 6;
  const long n = (long)blockIdx.x * 64 + lane;
  const int d0 = seg * 32;
  float v[32];
  float s1 = 0.f, s2 = 0.f;
#pragma unroll
  for (int i = 0; i < 32; ++i) {
    float t = bf2f(a[(long)(d0 + i) * 16384 + n]) + bf2f(b[(long)(d0 + i) * 16384 + n]);
    v[i] = t; s1 += t; s2 += t * t;
  }
  red[0][seg][lane] = s1; red[1][seg][lane] = s2;
  __syncthreads();
  s1 = 0.f; s2 = 0.f;
#pragma unroll
  for (int s = 0; s < 16; ++s) { s1 += red[0][s][lane]; s2 += red[1][s][lane]; }
  float mean = s1 * (1.f / 512.f);
  float var = s2 * (1.f / 512.f) - mean * mean;
  float rstd = rsqrtf(var + 1e-5f);
  __syncthreads();
  s1 = 0.f; s2 = 0.f;
#pragma unroll
  for (int i = 0; i < 32; ++i) {
    float y = (v[i] - mean) * rstd * w1[d0 + i] + b1[d0 + i];
    v[i] = y; s1 += y; s2 += y * y;
  }
  red[0][seg][lane] = s1; red[1][seg][lane] = s2;
  __syncthreads();
  s1 = 0.f; s2 = 0.f;
#pragma unroll
  for (int s = 0; s < 16; ++s) { s1 += red[0][s][lane]; s2 += red[1][s][lane]; }
  mean = s1 * (1.f / 512.f);
  var = s2 * (1.f / 512.f) - mean * mean;
  rstd = rsqrtf(var + 1e-5f);
#pragma unroll
  for (int i = 0; i < 32; ++i) {
    float o = (v[i] - mean) * rstd * w2[d0 + i] + b2[d0 + i];
    out[(long)(d0 + i) * 16384 + n] = f2bf(o);
  }
}

extern "C" void kernel_launch(void* const* d_in, const int* in_sizes, int n_in,
                              void* d_out, int out_size, void* d_ws, size_t ws_size,
                              hipStream_t stream) {
  const float* x     = (const float*)d_in[0];
  const float* w_row = (const float*)d_in[1];
  const float* b_row = (const float*)d_in[2];
  const float* w_col = (const float*)d_in[3];
  const float* b_col = (const float*)d_in[4];
  const float* w_an1 = (const float*)d_in[5];
  const float* b_an1 = (const float*)d_in[6];
  const float* w_an2 = (const float*)d_in[7];
  const float* b_an2 = (const float*)d_in[8];
  const float* w_ff1 = (const float*)d_in[9];
  const float* b_ff1 = (const float*)d_in[10];
  const float* w_ff2 = (const float*)d_in[11];
  const float* b_ff2 = (const float*)d_in[12];
  const float* w_ln1 = (const float*)d_in[13];
  const float* b_ln1 = (const float*)d_in[14];
  const float* w_ln2 = (const float*)d_in[15];
  const float* b_ln2 = (const float*)d_in[16];
  float* outp = (float*)d_out;

  char* Wb = (char*)d_ws;
  ushort* big    = (ushort*)Wb;                       // [2048][16384] bf16: qkv / ff1
  float*  sc     = (float*)(Wb + 50331648ull);        // scores fp32 (alias big rows 1536+)
  ushort* colbf  = (ushort*)(Wb + 71303168ull);       // col-attn out bf16
  ushort* P      = (ushort*)(Wb + 90177536ull);       // bf16 probs
  ushort* xbf    = (ushort*)(Wb + 100663296ull);      // x bf16 (dead after ln5)
  ushort* ff2bf  = (ushort*)(Wb + 100663296ull);      //   reused: ff2 out
  ushort* rowbf  = (ushort*)(Wb + 118489088ull);      // row-attn out bf16
  ushort* out1bf = (ushort*)(Wb + 136314880ull);      // LN5 out bf16
  ushort* hbf    = (ushort*)(Wb + 154140672ull);      // fused-LN out bf16
  ushort* wrowb  = (ushort*)(Wb + 171966464ull);      // weights bf16
  ushort* wcolb = wrowb + 786432;
  ushort* wff1b = wcolb + 786432;
  ushort* wff2b = wff1b + 1048576;

  const dim3 blk(256);
  const long HQ = 131072;  // per-head stride in qkv (8 ch * 16384)
  const long HS = 65536;   // per-head stride in scores/P

  // 0. bf16 conversions: x + all 4 weights (merged)
  cvt_kernel<<<8192, blk, 0, stream>>>((const float4*)x, (ushort4*)xbf, 2097152);
  cvtw_kernel<<<3584, blk, 0, stream>>>(
      (const float4*)w_row, (ushort4*)wrowb, (const float4*)w_col, (ushort4*)wcolb,
      (const float4*)w_ff1, (ushort4*)wff1b, (const float4*)w_ff2, (ushort4*)wff2b);

  // 1. qkv_row = W_row * x + b_row   [1536][16384] bf16
  gemm<0,1,true,false,1,false><<<dim3(128, 12, 1), blk, 0, stream>>>(
      big, wrowb, xbf, b_row, 512, 512, 16384, 16384, 0, 0, 0);
  // 2. scores[h][i][j] = sum_cs Q[cs][i] K[cs][j]
  gemm<1,1,false,false,0,false><<<dim3(2, 2, 64), blk, 0, stream>>>(
      sc, big, big + (long)512 * 16384, nullptr, 512, 256, 256, 256, HQ, HQ, HS);
  // 3. softmax over j -> bf16 P
  softmax_kernel<<<4096, blk, 0, stream>>>(sc, P);
  // 4. row_out[cs][i] = sum_j P[i][j] V[cs][j]  (bf16 transposed epilogue)
  gemm<0,0,false,false,1,true><<<dim3(4, 2, 64), blk, 0, stream>>>(
      rowbf, P, big + (long)1024 * 16384, nullptr, 256, 256, 256, 256, HS, HQ, HQ);
  // 5. out1 = LN(x + row_out) -> out1bf
  ln_kernel<true, 0><<<256, dim3(1024), 0, stream>>>(out1bf, xbf, rowbf, w_an1, b_an1);
  // 6. qkv_col = W_col * out1 + b_col  -> big (bf16)
  gemm<0,1,true,false,1,false><<<dim3(128, 12, 1), blk, 0, stream>>>(
      big, wcolb, out1bf, b_col, 512, 512, 16384, 16384, 0, 0, 0);
  // 7. column attention -> colbf
  colattn_kernel<<<4096, blk, 0, stream>>>(big, colbf);
  // 8+9. h = LN(LN(out1 + col_out)*w_an2+b_an2)*w_ln1+b_ln1 -> hbf
  ln_fuse_kernel<<<256, dim3(1024), 0, stream>>>(hbf, out1bf, colbf,
                                                 w_an2, b_an2, w_ln1, b_ln1);
  // 10. ff1 = relu(W_ff1 * h + b_ff1) -> big [2048][16384] bf16
  gemm<0,1,true,true,1,false><<<dim3(128, 16, 1), blk, 0, stream>>>(
      big, wff1b, hbf, b_ff1, 512, 512, 16384, 16384, 0, 0, 0);
  // 11. ff2 = W_ff2 * ff1 + b_ff2 -> ff2bf
  gemm<0,1,true,false,1,false><<<dim3(128, 4, 1), blk, 0, stream>>>(
      ff2bf, wff2b, big, b_ff2, 2048, 2048, 16384, 16384, 0, 0, 0);
  // 12. out = LN(h + ff2) -> d_out (fp32)
  ln_kernel<true, 1><<<256, dim3(1024), 0, stream>>>(outp, hbf, ff2bf, w_ln2, b_ln2);
}